// Round 10
// baseline (993.779 us; speedup 1.0000x reference)
//
#include <hip/hip_runtime.h>
#include <hip/hip_cooperative_groups.h>

namespace cg = cooperative_groups;

// Problem constants (fixed by the reference)
#define N_NODES 16384
#define N_EDGES 262144
#define E_TOT   (N_EDGES + N_NODES)   // edges + self loops = 278528
#define NEG_SLOPE 0.2f
#define SLOTS 64                      // fixed-slot CSR capacity (P(deg>64)~1e-55)
#define SCAT_BLOCKS ((E_TOT + 255) / 256)   // 1088
#define GRID_MAX 1024                 // target: 4 blocks/CU (LDS 36KBx4<=160)

typedef __attribute__((ext_vector_type(8))) short short8;
typedef __attribute__((ext_vector_type(4))) float floatx4;
typedef __attribute__((ext_vector_type(4))) int intx4;

__device__ __forceinline__ float bf2f(ushort u) {
    return __uint_as_float(((unsigned)u) << 16);
}
__device__ __forceinline__ ushort f2bf(float f) {
    unsigned u = __float_as_uint(f);
    u += 0x7fffu + ((u >> 16) & 1u);   // round-to-nearest-even
    return (ushort)(u >> 16);
}
__device__ __forceinline__ float leaky(float x) {
    return x > 0.f ? x : NEG_SLOPE * x;
}

// prep phase ranges (all multiples of 256)
#define PREP_CAST   524288
#define PREP_T1     (PREP_CAST + 65536)
#define PREP_T2     (PREP_T1 + 131072)
#define PREP_Z      (PREP_T2 + 262144)
#define PREP_ZA     (PREP_Z + 4096)
#define PREP_V      (PREP_ZA + 24576)
#define PREP_TOT    (PREP_V + 131072)
#define PREP_VB     (PREP_TOT / 256)        // 4464 virtual blocks

#define GM 128
#define GN 128
#define GK 64
#define LDK2 72

struct MegaP {
    const float *x, *Wfc, *bfc, *W1, *a1s, *a1d, *b1, *W2, *a2s, *a2d, *b2;
    const int* adj;
    float* out;
    ushort *xb, *h0b, *hub, *g1b, *WfcT, *W1T, *W2T;
    int *counts, *esrc;
    float *als1, *ald1, *als2, *ald2, *v1s, *v1d, *v2s, *v2d;
};

// ---------------------------------------------------------------------------
// Shared per-thread PREP step (cast x, transposes, zeroing, v-dots):
//   v1s[h*256+k] = sum_c W1[k,h*256+c]*a1s[h,c];  v2s[k] = sum_c W2[k,c]*a2s[c]
// ---------------------------------------------------------------------------
__device__ __forceinline__ void prep_step(int idx, const MegaP& p) {
    if (idx < PREP_CAST) {
        floatx4 v0 = *(const floatx4*)(p.x + (size_t)idx * 8);
        floatx4 v1 = *(const floatx4*)(p.x + (size_t)idx * 8 + 4);
        short8 r;
        r[0] = (short)f2bf(v0[0]); r[1] = (short)f2bf(v0[1]);
        r[2] = (short)f2bf(v0[2]); r[3] = (short)f2bf(v0[3]);
        r[4] = (short)f2bf(v1[0]); r[5] = (short)f2bf(v1[1]);
        r[6] = (short)f2bf(v1[2]); r[7] = (short)f2bf(v1[3]);
        *(short8*)(p.xb + (size_t)idx * 8) = r;
    } else if (idx < PREP_T1) {
        int t = idx - PREP_CAST;               // K=256, N=256
        int k = t >> 8, n = t & 255;
        p.WfcT[n * 256 + k] = f2bf(p.Wfc[t]);
    } else if (idx < PREP_T2) {
        int t = idx - PREP_T1;                 // K=256, N=512
        int k = t >> 9, n = t & 511;
        p.W1T[n * 256 + k] = f2bf(p.W1[t]);
    } else if (idx < PREP_Z) {
        int t = idx - PREP_T2;                 // K=512, N=512
        int k = t >> 9, n = t & 511;
        p.W2T[n * 512 + k] = f2bf(p.W2[t]);
    } else if (idx < PREP_ZA) {
        int t = idx - PREP_Z;
        *(intx4*)(p.counts + t * 4) = (intx4){0, 0, 0, 0};
    } else if (idx < PREP_V) {
        int t = idx - PREP_ZA;                 // zero als1/ald1/als2/ald2 block
        *(intx4*)((int*)p.als1 + t * 4) = (intx4){0, 0, 0, 0};
    } else if (idx < PREP_TOT) {
        int t = idx - PREP_V;                  // 2048 waves, 1 output each
        int w = t >> 6, lane = t & 63;
        int grp = w >> 9;                      // 0:v1s 1:v1d 2:v2s 3:v2d
        int o = w & 511;
        float sum;
        if (grp < 2) {
            const float* a = grp ? p.a1d : p.a1s;      // [2][256]
            int h = o >> 8, k = o & 255;
            const float* wr = p.W1 + (size_t)k * 512 + h * 256;
            const float* ar = a + h * 256;
            floatx4 wv = *(const floatx4*)(wr + lane * 4);
            floatx4 av = *(const floatx4*)(ar + lane * 4);
            sum = wv[0]*av[0] + wv[1]*av[1] + wv[2]*av[2] + wv[3]*av[3];
        } else {
            const float* a = (grp == 2) ? p.a2s : p.a2d;   // [512]
            const float* wr = p.W2 + (size_t)o * 512;
            floatx4 w0 = *(const floatx4*)(wr + lane * 8);
            floatx4 w1 = *(const floatx4*)(wr + lane * 8 + 4);
            floatx4 a0 = *(const floatx4*)(a + lane * 8);
            floatx4 a1 = *(const floatx4*)(a + lane * 8 + 4);
            sum = w0[0]*a0[0] + w0[1]*a0[1] + w0[2]*a0[2] + w0[3]*a0[3]
                + w1[0]*a1[0] + w1[1]*a1[1] + w1[2]*a1[2] + w1[3]*a1[3];
        }
#pragma unroll
        for (int msk = 1; msk < 64; msk <<= 1) sum += __shfl_xor(sum, msk, 64);
        if (lane == 0) {
            float* dst = (grp == 0) ? p.v1s : (grp == 1) ? p.v1d
                        : (grp == 2) ? p.v2s : p.v2d;
            dst[o] = sum;
        }
    }
}

// shared per-thread fixed-slot CSR scatter step
__device__ __forceinline__ void scatter_step(int e, const int* __restrict__ adj,
                                             int* __restrict__ counts,
                                             int* __restrict__ esrc) {
    if (e < E_TOT) {
        int s, d;
        if (e < N_EDGES) { s = adj[e]; d = adj[N_EDGES + e]; }
        else             { s = e - N_EDGES; d = s; }
        int pos = atomicAdd(&counts[d], 1);
        esrc[(d << 6) + pos] = s;
    }
}

// ---------------------------------------------------------------------------
// GEMM body (R14-proven schedule, FROZEN): 128x128 tile, BK=64, 4 waves
// (2x2 of 64x64), 4x4 MFMA tiles/wave, single LDS buffer. Pipelined staging:
// raw s_barrier + lgkmcnt(0)-only waits (rule #18 sched_barriers); next-tile
// global loads issued right after the writes-visible barrier, in flight
// across the MFMA phase. OPTIONAL fused attention-logit epilogue.
// mfma_f32_16x16x32_bf16 layouts (HW-verified):
//   A frag: A[m=lane&15][k=(lane>>4)*8 + j]
//   B frag: B[k=(lane>>4)*8 + j][n=lane&15]  (from BT rows)
//   C/D:    col=lane&15, row=(lane>>4)*4 + reg
// ---------------------------------------------------------------------------
__device__ __forceinline__ void gemm_body(const ushort* __restrict__ A,
                                          int lda, int agrp,
                                          const ushort* __restrict__ BT,
                                          const float* __restrict__ bias,
                                          ushort* __restrict__ C,
                                          float* __restrict__ Cf,
                                          int Nc, int K, int relu,
                                          const float* __restrict__ vs,
                                          const float* __restrict__ vd,
                                          float* __restrict__ als,
                                          float* __restrict__ ald,
                                          int heads, int bm, int bn,
                                          ushort* __restrict__ As,
                                          ushort* __restrict__ Bs) {
    int tid = threadIdx.x, wave = tid >> 6, lane = tid & 63;
    int quad = lane >> 4, l16 = lane & 15;
    int wm = (wave & 1) * 64, wn = (wave >> 1) * 64;
    int abase = (bn >> 8) * agrp;

    floatx4 acc[4][4];
#pragma unroll
    for (int mi = 0; mi < 4; mi++)
#pragma unroll
        for (int ni = 0; ni < 4; ni++)
            acc[mi][ni] = (floatx4){0.f, 0.f, 0.f, 0.f};

    int srow[4], scol[4];
#pragma unroll
    for (int t = 0; t < 4; t++) {
        int ci = tid + 256 * t;
        srow[t] = ci >> 3;
        scol[t] = (ci & 7) * 8;
    }

    short8 av[4], bv[4];
#pragma unroll
    for (int t = 0; t < 4; t++) {
        av[t] = *(const short8*)(A + (size_t)(bm + srow[t]) * lda + abase + scol[t]);
        bv[t] = *(const short8*)(BT + (size_t)(bn + srow[t]) * K + scol[t]);
    }

    for (int kb = 0; kb < K; kb += GK) {
        if (kb) {
            asm volatile("s_waitcnt lgkmcnt(0)" ::: "memory");
            __builtin_amdgcn_sched_barrier(0);
            __builtin_amdgcn_s_barrier();
            __builtin_amdgcn_sched_barrier(0);
        }
#pragma unroll
        for (int t = 0; t < 4; t++) {
            *(short8*)&As[srow[t] * LDK2 + scol[t]] = av[t];
            *(short8*)&Bs[srow[t] * LDK2 + scol[t]] = bv[t];
        }
        asm volatile("s_waitcnt lgkmcnt(0)" ::: "memory");
        __builtin_amdgcn_sched_barrier(0);
        __builtin_amdgcn_s_barrier();
        __builtin_amdgcn_sched_barrier(0);

        if (kb + GK < K) {
#pragma unroll
            for (int t = 0; t < 4; t++) {
                av[t] = *(const short8*)(A + (size_t)(bm + srow[t]) * lda + abase + kb + GK + scol[t]);
                bv[t] = *(const short8*)(BT + (size_t)(bn + srow[t]) * K + kb + GK + scol[t]);
            }
            __builtin_amdgcn_sched_barrier(0);
        }

#pragma unroll
        for (int kk = 0; kk < GK; kk += 32) {
            short8 af[4], bf[4];
#pragma unroll
            for (int mi = 0; mi < 4; mi++)
                af[mi] = *(const short8*)&As[(wm + mi * 16 + l16) * LDK2 + kk + quad * 8];
#pragma unroll
            for (int ni = 0; ni < 4; ni++)
                bf[ni] = *(const short8*)&Bs[(wn + ni * 16 + l16) * LDK2 + kk + quad * 8];
#pragma unroll
            for (int mi = 0; mi < 4; mi++)
#pragma unroll
                for (int ni = 0; ni < 4; ni++)
                    acc[mi][ni] = __builtin_amdgcn_mfma_f32_16x16x32_bf16(
                        af[mi], bf[ni], acc[mi][ni], 0, 0, 0);
        }
    }

    // leave LDS barrier state clean for any subsequent reuse of As/Bs
    asm volatile("s_waitcnt lgkmcnt(0)" ::: "memory");
    __builtin_amdgcn_s_barrier();

#pragma unroll
    for (int mi = 0; mi < 4; mi++) {
        int row = bm + wm + mi * 16 + quad * 4;
#pragma unroll
        for (int ni = 0; ni < 4; ni++) {
            int col = bn + wn + ni * 16 + l16;
            float bv2 = bias ? bias[col] : 0.f;
#pragma unroll
            for (int i = 0; i < 4; i++) {
                float v = acc[mi][ni][i] + bv2;
                if (relu) v = fmaxf(v, 0.f);
                acc[mi][ni][i] = v;
                if (Cf) Cf[(size_t)(row + i) * Nc + col] = v;
                else    C[(size_t)(row + i) * Nc + col] = f2bf(v);
            }
        }
    }

    if (als) {
        if (heads == 2) {
            float s0[4], s1[4], d0[4], d1[4];
#pragma unroll
            for (int ni = 0; ni < 4; ni++) {
                int col = bn + wn + ni * 16 + l16;   // Nc == 256 here
                s0[ni] = vs[col];  s1[ni] = vs[256 + col];
                d0[ni] = vd[col];  d1[ni] = vd[256 + col];
            }
#pragma unroll
            for (int mi = 0; mi < 4; mi++) {
#pragma unroll
                for (int i = 0; i < 4; i++) {
                    float aS0 = 0.f, aS1 = 0.f, aD0 = 0.f, aD1 = 0.f;
#pragma unroll
                    for (int ni = 0; ni < 4; ni++) {
                        float vv = acc[mi][ni][i];
                        aS0 += vv * s0[ni]; aS1 += vv * s1[ni];
                        aD0 += vv * d0[ni]; aD1 += vv * d1[ni];
                    }
#pragma unroll
                    for (int msk = 1; msk < 16; msk <<= 1) {
                        aS0 += __shfl_xor(aS0, msk, 64);
                        aS1 += __shfl_xor(aS1, msk, 64);
                        aD0 += __shfl_xor(aD0, msk, 64);
                        aD1 += __shfl_xor(aD1, msk, 64);
                    }
                    if (l16 == 0) {
                        int row = bm + wm + mi * 16 + quad * 4 + i;
                        atomicAdd(&als[row * 2],     aS0);
                        atomicAdd(&als[row * 2 + 1], aS1);
                        atomicAdd(&ald[row * 2],     aD0);
                        atomicAdd(&ald[row * 2 + 1], aD1);
                    }
                }
            }
        } else {
            float aS[4], aD[4];
#pragma unroll
            for (int ni = 0; ni < 4; ni++) {
                int col = bn + wn + ni * 16 + l16;
                aS[ni] = vs[col];
                aD[ni] = vd[col];
            }
#pragma unroll
            for (int mi = 0; mi < 4; mi++) {
#pragma unroll
                for (int i = 0; i < 4; i++) {
                    float dS = 0.f, dD = 0.f;
#pragma unroll
                    for (int ni = 0; ni < 4; ni++) {
                        dS += acc[mi][ni][i] * aS[ni];
                        dD += acc[mi][ni][i] * aD[ni];
                    }
#pragma unroll
                    for (int msk = 1; msk < 16; msk <<= 1) {
                        dS += __shfl_xor(dS, msk, 64);
                        dD += __shfl_xor(dD, msk, 64);
                    }
                    if (l16 == 0) {
                        int row = bm + wm + mi * 16 + quad * 4 + i;
                        atomicAdd(&als[row], dS);
                        atomicAdd(&ald[row], dD);
                    }
                }
            }
        }
    }
}

// ---------------------------------------------------------------------------
// Aggregation body (R18-proven 4-wide, FROZEN): single-pass segment softmax
// + aggregation, one wave per node, fixed-slot CSR (base=n*64, deg=counts[n]).
// Logits O(+-5) -> exp without max-subtraction; identical alpha.
// ---------------------------------------------------------------------------
__device__ __forceinline__ void agg_body(const ushort* __restrict__ h,
                                         const float* __restrict__ als,
                                         const float* __restrict__ ald,
                                         const int* __restrict__ counts,
                                         const int* __restrict__ esrc,
                                         ushort* __restrict__ outb,
                                         int heads, int vb) {
    int wave = threadIdx.x >> 6, lane = threadIdx.x & 63;
    int n = vb * 4 + wave;
    int base = n << 6;
    int deg  = counts[n];

    int myhead = (heads == 2) ? (lane >> 5) : 0;
    int cs = (heads == 2) ? ((lane & 31) * 8) : (lane * 8);
    int stride = (heads == 2) ? 256 : 512;

    float aldh0 = ald[n * heads];
    float aldh1 = (heads == 2) ? ald[n * heads + 1] : 0.f;
    const ushort* hc = h + cs;

    float acc[8];
#pragma unroll
    for (int q = 0; q < 8; q++) acc[q] = 0.f;
    float ws0 = 0.f, ws1 = 0.f;

    for (int cb = 0; cb < deg; cb += 64) {
        int i = cb + lane;
        int sv = 0;
        float w0 = 0.f, w1 = 0.f;
        if (i < deg) {
            sv = esrc[base + i];
            w0 = __expf(leaky(als[sv * heads] + aldh0));
            if (heads == 2) w1 = __expf(leaky(als[sv * 2 + 1] + aldh1));
            ws0 += w0; ws1 += w1;
        }
        int cnt = min(64, deg - cb);
        int j = 0;
        for (; j + 4 <= cnt; j += 4) {
            int sj0 = __shfl(sv, j, 64);
            int sj1 = __shfl(sv, j + 1, 64);
            int sj2 = __shfl(sv, j + 2, 64);
            int sj3 = __shfl(sv, j + 3, 64);
            float a00 = __shfl(w0, j, 64),     a01 = __shfl(w1, j, 64);
            float a10 = __shfl(w0, j + 1, 64), a11 = __shfl(w1, j + 1, 64);
            float a20 = __shfl(w0, j + 2, 64), a21 = __shfl(w1, j + 2, 64);
            float a30 = __shfl(w0, j + 3, 64), a31 = __shfl(w1, j + 3, 64);
            float al0 = myhead ? a01 : a00;
            float al1 = myhead ? a11 : a10;
            float al2 = myhead ? a21 : a20;
            float al3 = myhead ? a31 : a30;
            short8 h0v = *(const short8*)(hc + (size_t)sj0 * stride);
            short8 h1v = *(const short8*)(hc + (size_t)sj1 * stride);
            short8 h2v = *(const short8*)(hc + (size_t)sj2 * stride);
            short8 h3v = *(const short8*)(hc + (size_t)sj3 * stride);
#pragma unroll
            for (int q = 0; q < 8; q++) {
                acc[q] += al0 * bf2f((ushort)h0v[q]);
                acc[q] += al1 * bf2f((ushort)h1v[q]);
                acc[q] += al2 * bf2f((ushort)h2v[q]);
                acc[q] += al3 * bf2f((ushort)h3v[q]);
            }
        }
        for (; j < cnt; j++) {
            int s = __shfl(sv, j, 64);
            float a0 = __shfl(w0, j, 64), a1 = __shfl(w1, j, 64);
            float al = myhead ? a1 : a0;
            short8 hv = *(const short8*)(hc + (size_t)s * stride);
#pragma unroll
            for (int q = 0; q < 8; q++) acc[q] += al * bf2f((ushort)hv[q]);
        }
    }

#pragma unroll
    for (int msk = 1; msk < 64; msk <<= 1) {
        ws0 += __shfl_xor(ws0, msk, 64);
        ws1 += __shfl_xor(ws1, msk, 64);
    }
    float inv = 1.f / ((myhead ? ws1 : ws0) + 1e-16f);

    short8 r;
#pragma unroll
    for (int q = 0; q < 8; q++) r[q] = (short)f2bf(acc[q] * inv);
    *(short8*)(outb + (size_t)n * 512 + lane * 8) = r;
}

// ---------------------------------------------------------------------------
// R22 mega kernel (cooperative): all 6 phases, grid.sync between, grid-stride
// by runtime gridDim.x. __threadfence before AND after each sync (release +
// acquire, cross-XCD belt-and-braces). Phase bodies identical to fallback.
// ---------------------------------------------------------------------------
__global__ __launch_bounds__(256, 4) void k_mega(MegaP p) {
    cg::grid_group grid = cg::this_grid();
    __shared__ ushort As[GM * LDK2];   // 18 KB
    __shared__ ushort Bs[GN * LDK2];   // 18 KB
    int tidx = threadIdx.x;
    int gstride = gridDim.x;

    // P0: prep
    for (int vb = blockIdx.x; vb < PREP_VB; vb += gstride)
        prep_step(vb * 256 + tidx, p);
    __threadfence(); grid.sync(); __threadfence();

    // P1: gemm1 (vb<256, first: long pole) || scatter
    for (int vb = blockIdx.x; vb < 256 + SCAT_BLOCKS; vb += gstride) {
        if (vb < 256) {
            int bm = (vb & 127) * GM, bn = (vb >> 7) * GN;
            gemm_body(p.xb, 256, 0, p.WfcT, p.bfc, p.h0b, nullptr, 256, 256, 1,
                      p.v1s, p.v1d, p.als1, p.ald1, 2, bm, bn, As, Bs);
        } else {
            scatter_step((vb - 256) * 256 + tidx, p.adj, p.counts, p.esrc);
        }
    }
    __threadfence(); grid.sync(); __threadfence();

    // P2: agg1 (h0 -> aggcat [N,512])
    for (int vb = blockIdx.x; vb < N_NODES / 4; vb += gstride)
        agg_body(p.h0b, p.als1, p.ald1, p.counts, p.esrc, p.hub, 2, vb);
    __threadfence(); grid.sync(); __threadfence();

    // P3: gemm2 (grouped aggcat@W1 -> g1, + logits2)
    for (int vb = blockIdx.x; vb < 512; vb += gstride) {
        int bm = (vb & 127) * GM, bn = (vb >> 7) * GN;
        gemm_body(p.hub, 512, 256, p.W1T, p.b1, p.g1b, nullptr, 512, 256, 1,
                  p.v2s, p.v2d, p.als2, p.ald2, 1, bm, bn, As, Bs);
    }
    __threadfence(); grid.sync(); __threadfence();

    // P4: agg2 (g1 -> agg2 [N,512])
    for (int vb = blockIdx.x; vb < N_NODES / 4; vb += gstride)
        agg_body(p.g1b, p.als2, p.ald2, p.counts, p.esrc, p.hub, 1, vb);
    __threadfence(); grid.sync(); __threadfence();

    // P5: gemm3 (agg2@W2 -> out fp32)
    for (int vb = blockIdx.x; vb < 512; vb += gstride) {
        int bm = (vb & 127) * GM, bn = (vb >> 7) * GN;
        gemm_body(p.hub, 512, 0, p.W2T, p.b2, nullptr, p.out, 512, 512, 1,
                  nullptr, nullptr, nullptr, nullptr, 0, bm, bn, As, Bs);
    }
}

// ---------------------------------------------------------------------------
// Fallback kernels (R20-proven multi-dispatch path; 222.7 us measured)
// ---------------------------------------------------------------------------
__global__ __launch_bounds__(256) void k_prep_g(MegaP p) {
    prep_step(blockIdx.x * 256 + threadIdx.x, p);
}

__global__ __launch_bounds__(256) void k_scat_gemm1_g(MegaP p) {
    __shared__ ushort As[GM * LDK2];
    __shared__ ushort Bs[GN * LDK2];
    int bx = blockIdx.x;
    if (bx >= 256) {
        scatter_step((bx - 256) * 256 + threadIdx.x, p.adj, p.counts, p.esrc);
        return;
    }
    int bm = (bx & 127) * GM, bn = (bx >> 7) * GN;
    gemm_body(p.xb, 256, 0, p.WfcT, p.bfc, p.h0b, nullptr, 256, 256, 1,
              p.v1s, p.v1d, p.als1, p.ald1, 2, bm, bn, As, Bs);
}

__global__ __launch_bounds__(256) void k_gemm2_g(MegaP p) {
    __shared__ ushort As[GM * LDK2];
    __shared__ ushort Bs[GN * LDK2];
    gemm_body(p.hub, 512, 256, p.W1T, p.b1, p.g1b, nullptr, 512, 256, 1,
              p.v2s, p.v2d, p.als2, p.ald2, 1,
              blockIdx.x * GM, blockIdx.y * GN, As, Bs);
}

__global__ __launch_bounds__(256) void k_gemm3_g(MegaP p) {
    __shared__ ushort As[GM * LDK2];
    __shared__ ushort Bs[GN * LDK2];
    gemm_body(p.hub, 512, 0, p.W2T, p.b2, nullptr, p.out, 512, 512, 1,
              nullptr, nullptr, nullptr, nullptr, 0,
              blockIdx.x * GM, blockIdx.y * GN, As, Bs);
}

__global__ __launch_bounds__(256) void k_agg1_g(MegaP p) {
    agg_body(p.h0b, p.als1, p.ald1, p.counts, p.esrc, p.hub, 2, blockIdx.x);
}
__global__ __launch_bounds__(256) void k_agg2_g(MegaP p) {
    agg_body(p.g1b, p.als2, p.ald2, p.counts, p.esrc, p.hub, 1, blockIdx.x);
}

// ---------------------------------------------------------------------------
// R22 launcher: cooperative mega-kernel if (and only if) host queries say it
// can launch; rc-checked with fallback to the proven 6-dispatch path.
// ---------------------------------------------------------------------------
extern "C" void kernel_launch(void* const* d_in, const int* in_sizes, int n_in,
                              void* d_out, int out_size, void* d_ws, size_t ws_size,
                              hipStream_t stream) {
    char* ws = (char*)d_ws;
    size_t off = 0;
    auto alloc = [&](size_t bytes) -> void* {
        void* p = ws + off;
        off += (bytes + 255) & ~(size_t)255;
        return p;
    };
    MegaP p;
    p.x   = (const float*)d_in[0];
    p.adj = (const int*)d_in[1];
    p.Wfc = (const float*)d_in[2];
    p.bfc = (const float*)d_in[3];
    p.W1  = (const float*)d_in[4];
    p.a1s = (const float*)d_in[5];
    p.a1d = (const float*)d_in[6];
    p.b1  = (const float*)d_in[7];
    p.W2  = (const float*)d_in[8];
    p.a2s = (const float*)d_in[9];
    p.a2d = (const float*)d_in[10];
    p.b2  = (const float*)d_in[11];
    p.out = (float*)d_out;

    p.xb   = (ushort*)alloc((size_t)N_NODES * 256 * 2);
    p.h0b  = (ushort*)alloc((size_t)N_NODES * 256 * 2);
    p.hub  = (ushort*)alloc((size_t)N_NODES * 512 * 2);  // aggcat, then agg2
    p.g1b  = (ushort*)alloc((size_t)N_NODES * 512 * 2);
    p.counts = (int*)alloc(N_NODES * 4);
    p.esrc   = (int*)alloc((size_t)N_NODES * SLOTS * 4); // fixed-slot CSR
    p.WfcT = (ushort*)alloc(256 * 256 * 2);
    p.W1T  = (ushort*)alloc(512 * 256 * 2);
    p.W2T  = (ushort*)alloc(512 * 512 * 2);
    // als/ald block: contiguous (256B-multiple sizes -> no alloc gaps),
    // zeroed as one segment in prep (98304 floats).
    p.als1 = (float*)alloc(N_NODES * 2 * 4);   // 32768 f
    p.ald1 = (float*)alloc(N_NODES * 2 * 4);   // 32768 f
    p.als2 = (float*)alloc(N_NODES * 4);       // 16384 f
    p.ald2 = (float*)alloc(N_NODES * 4);       // 16384 f
    p.v1s  = (float*)alloc(512 * 4);
    p.v1d  = (float*)alloc(512 * 4);
    p.v2s  = (float*)alloc(512 * 4);
    p.v2d  = (float*)alloc(512 * 4);

    // decide coop grid once (host-side queries only; cached)
    static int coop_grid = -2;
    if (coop_grid == -2) {
        int dev = 0, coop = 0, cu = 0, bpc = 0;
        hipGetDevice(&dev);
        hipDeviceGetAttribute(&coop, hipDeviceAttributeCooperativeLaunch, dev);
        hipDeviceGetAttribute(&cu, hipDeviceAttributeMultiprocessorCount, dev);
        hipError_t e = hipOccupancyMaxActiveBlocksPerMultiprocessor(
            &bpc, k_mega, 256, 0);
        if (coop && e == hipSuccess && bpc >= 1 && cu > 0) {
            long g = (long)bpc * cu;
            coop_grid = (int)(g < GRID_MAX ? g : GRID_MAX);
        } else {
            coop_grid = -1;
        }
    }

    bool done = false;
    if (coop_grid > 0) {
        void* kargs[] = { (void*)&p };
        hipError_t rc = hipLaunchCooperativeKernel(
            (const void*)k_mega, dim3(coop_grid), dim3(256), kargs, 0, stream);
        if (rc == hipSuccess) done = true;
        else { coop_grid = -1; (void)hipGetLastError(); }
    }

    if (!done) {
        // proven 6-dispatch path (R20)
        k_prep_g<<<PREP_VB, 256, 0, stream>>>(p);
        k_scat_gemm1_g<<<256 + SCAT_BLOCKS, 256, 0, stream>>>(p);
        k_agg1_g<<<N_NODES / 4, 256, 0, stream>>>(p);
        k_gemm2_g<<<dim3(128, 4), 256, 0, stream>>>(p);
        k_agg2_g<<<N_NODES / 4, 256, 0, stream>>>(p);
        k_gemm3_g<<<dim3(128, 4), 256, 0, stream>>>(p);
    }
}

// Round 11
// 220.684 us; speedup vs baseline: 4.5032x; 4.5032x over previous
//
#include <hip/hip_runtime.h>

// Problem constants (fixed by the reference)
#define N_NODES 16384
#define N_EDGES 262144
#define E_TOT   (N_EDGES + N_NODES)   // edges + self loops = 278528
#define NEG_SLOPE 0.2f
#define SLOTS 64                      // fixed-slot CSR capacity (P(deg>64)~1e-55)

typedef __attribute__((ext_vector_type(8))) short short8;
typedef __attribute__((ext_vector_type(4))) float floatx4;
typedef __attribute__((ext_vector_type(4))) int intx4;

__device__ __forceinline__ float bf2f(ushort u) {
    return __uint_as_float(((unsigned)u) << 16);
}
__device__ __forceinline__ ushort f2bf(float f) {
    unsigned u = __float_as_uint(f);
    u += 0x7fffu + ((u >> 16) & 1u);   // round-to-nearest-even
    return (ushort)(u >> 16);
}
__device__ __forceinline__ float leaky(float x) {
    return x > 0.f ? x : NEG_SLOPE * x;
}

// ---------------------------------------------------------------------------
// Fused prep (R23: x-cast phase DELETED -- gemm1 reads x fp32 directly):
// 3 weight transposes, counts zeroing, als/ald zeroing, and the attention-
// projection vectors:
//   v1s[h*256+k] = sum_c W1[k, h*256+c] * a1s[h,c]   (likewise v1d)
//   v2s[k]       = sum_c W2[k, c]       * a2s[c]     (likewise v2d)
// These let logits be computed from PRE-GEMM activations:
//   als1[n,h] = relu(h0[n]) . v1s[h]     als2[n] = g1[n] . v2s
// ---------------------------------------------------------------------------
#define PREP_T1     65536                  // transpose Wfc 256x256
#define PREP_T2     (PREP_T1 + 131072)     // transpose W1 256x512
#define PREP_Z      (PREP_T2 + 262144)     // transpose W2 512x512
#define PREP_ZA     (PREP_Z + 4096)        // zero counts
#define PREP_V      (PREP_ZA + 24576)      // zero als/ald block
#define PREP_TOT    (PREP_V + 131072)      // v-dots; total 618496 -> 2416 blk

__global__ __launch_bounds__(256) void k_prep(const float* __restrict__ Wfc,
                                              ushort* __restrict__ WfcT,
                                              const float* __restrict__ W1,
                                              ushort* __restrict__ W1T,
                                              const float* __restrict__ W2,
                                              ushort* __restrict__ W2T,
                                              int* __restrict__ counts,
                                              int* __restrict__ alzero,
                                              const float* __restrict__ a1s,
                                              const float* __restrict__ a1d,
                                              const float* __restrict__ a2s,
                                              const float* __restrict__ a2d,
                                              float* __restrict__ v1s,
                                              float* __restrict__ v1d,
                                              float* __restrict__ v2s,
                                              float* __restrict__ v2d) {
    int idx = blockIdx.x * 256 + threadIdx.x;
    if (idx < PREP_T1) {
        int t = idx;                           // K=256, N=256
        int k = t >> 8, n = t & 255;
        WfcT[n * 256 + k] = f2bf(Wfc[t]);
    } else if (idx < PREP_T2) {
        int t = idx - PREP_T1;                 // K=256, N=512
        int k = t >> 9, n = t & 511;
        W1T[n * 256 + k] = f2bf(W1[t]);
    } else if (idx < PREP_Z) {
        int t = idx - PREP_T2;                 // K=512, N=512
        int k = t >> 9, n = t & 511;
        W2T[n * 512 + k] = f2bf(W2[t]);
    } else if (idx < PREP_ZA) {
        int t = idx - PREP_Z;
        *(intx4*)(counts + t * 4) = (intx4){0, 0, 0, 0};
    } else if (idx < PREP_V) {
        int t = idx - PREP_ZA;
        *(intx4*)(alzero + t * 4) = (intx4){0, 0, 0, 0};
    } else if (idx < PREP_TOT) {
        int t = idx - PREP_V;                  // 2048 waves, 1 output each
        int w = t >> 6, lane = t & 63;
        int grp = w >> 9;                      // 0:v1s 1:v1d 2:v2s 3:v2d
        int o = w & 511;
        float sum;
        if (grp < 2) {
            const float* a = grp ? a1d : a1s;          // [2][256]
            int h = o >> 8, k = o & 255;
            const float* wr = W1 + (size_t)k * 512 + h * 256;
            const float* ar = a + h * 256;
            floatx4 wv = *(const floatx4*)(wr + lane * 4);
            floatx4 av = *(const floatx4*)(ar + lane * 4);
            sum = wv[0]*av[0] + wv[1]*av[1] + wv[2]*av[2] + wv[3]*av[3];
        } else {
            const float* a = (grp == 2) ? a2s : a2d;   // [512]
            const float* wr = W2 + (size_t)o * 512;
            floatx4 w0 = *(const floatx4*)(wr + lane * 8);
            floatx4 w1 = *(const floatx4*)(wr + lane * 8 + 4);
            floatx4 a0 = *(const floatx4*)(a + lane * 8);
            floatx4 a1 = *(const floatx4*)(a + lane * 8 + 4);
            sum = w0[0]*a0[0] + w0[1]*a0[1] + w0[2]*a0[2] + w0[3]*a0[3]
                + w1[0]*a1[0] + w1[1]*a1[1] + w1[2]*a1[2] + w1[3]*a1[3];
        }
#pragma unroll
        for (int msk = 1; msk < 64; msk <<= 1) sum += __shfl_xor(sum, msk, 64);
        if (lane == 0) {
            float* dst = (grp == 0) ? v1s : (grp == 1) ? v1d
                        : (grp == 2) ? v2s : v2d;
            dst[o] = sum;
        }
    }
}

// ---------------------------------------------------------------------------
// FIXED-SLOT CSR build in ONE dispatch (R18-proven):
// esrc[d*64 + pos] = s with pos = atomicAdd(&counts[d],1); counts zeroed
// by k_prep. Degrees are Poisson(~17): P(deg > 64) ~ 1e-55 -> 64 slots safe.
// After this kernel counts[n]=deg(n).
// ---------------------------------------------------------------------------
__global__ __launch_bounds__(256) void k_scatter(const int* __restrict__ adj,
                                                 int* __restrict__ counts,
                                                 int* __restrict__ esrc) {
    int e = blockIdx.x * 256 + threadIdx.x;
    if (e < E_TOT) {
        int s, d;
        if (e < N_EDGES) { s = adj[e]; d = adj[N_EDGES + e]; }
        else             { s = e - N_EDGES; d = s; }
        int pos = atomicAdd(&counts[d], 1);
        esrc[(d << 6) + pos] = s;
    }
}

// ---------------------------------------------------------------------------
// 128x128-tile GEMM (R14-proven schedule, FROZEN) with OPTIONAL fused
// attention-logit epilogue. BK=64, 4 waves (2x2 of 64x64), 4x4 MFMA
// tiles/wave, single LDS buffer. Pipelined staging: raw s_barrier +
// lgkmcnt(0)-only waits (rule #18 sched_barriers); next-tile global loads
// issued right after the writes-visible barrier, in flight across the MFMA
// phase.
// R23: A may be fp32 (a_f32=1, gemm1 reads x directly). The fp32 path keeps
// RAW floatx4 loads in named registers at issue time and converts f2bf only
// at the ds_write site -- loads stay in flight across compute exactly as in
// the bf16 path (conversion pinned at write site, not issue site).
// mfma_f32_16x16x32_bf16 layouts (HW-verified):
//   A frag: A[m=lane&15][k=(lane>>4)*8 + j]
//   B frag: B[k=(lane>>4)*8 + j][n=lane&15]  (from BT rows)
//   C/D:    col=lane&15, row=(lane>>4)*4 + reg
// ---------------------------------------------------------------------------
#define GM 128
#define GN 128
#define GK 64
#define LDK2 72

__global__ __launch_bounds__(256) void gemm128(const void* __restrict__ Av,
                                               int a_f32, int lda, int agrp,
                                               const ushort* __restrict__ BT,
                                               const float* __restrict__ bias,
                                               ushort* __restrict__ C,
                                               float* __restrict__ Cf,
                                               int Nc, int K, int relu,
                                               const float* __restrict__ vs,
                                               const float* __restrict__ vd,
                                               float* __restrict__ als,
                                               float* __restrict__ ald,
                                               int heads) {
    __shared__ ushort As[GM * LDK2];   // 18 KB
    __shared__ ushort Bs[GN * LDK2];   // 18 KB
    int tid = threadIdx.x, wave = tid >> 6, lane = tid & 63;
    int quad = lane >> 4, l16 = lane & 15;
    int bm = blockIdx.x * GM, bn = blockIdx.y * GN;
    int wm = (wave & 1) * 64, wn = (wave >> 1) * 64;
    int abase = (bn >> 8) * agrp;

    const ushort* Ab = (const ushort*)Av;
    const float*  Af = (const float*)Av;

    floatx4 acc[4][4];
#pragma unroll
    for (int mi = 0; mi < 4; mi++)
#pragma unroll
        for (int ni = 0; ni < 4; ni++)
            acc[mi][ni] = (floatx4){0.f, 0.f, 0.f, 0.f};

    // staging coords (fixed per thread)
    int srow[4], scol[4];
#pragma unroll
    for (int t = 0; t < 4; t++) {
        int ci = tid + 256 * t;
        srow[t] = ci >> 3;
        scol[t] = (ci & 7) * 8;
    }

    // staging registers: bf16 path (av) or fp32 path (fa0/fa1), named sets
    short8 av[4], bv[4];
    floatx4 fa0[4], fa1[4];

    // prologue: load tile kb=0
    if (a_f32) {
#pragma unroll
        for (int t = 0; t < 4; t++) {
            const float* pa = Af + (size_t)(bm + srow[t]) * lda + abase + scol[t];
            fa0[t] = *(const floatx4*)pa;
            fa1[t] = *(const floatx4*)(pa + 4);
        }
    } else {
#pragma unroll
        for (int t = 0; t < 4; t++)
            av[t] = *(const short8*)(Ab + (size_t)(bm + srow[t]) * lda + abase + scol[t]);
    }
#pragma unroll
    for (int t = 0; t < 4; t++)
        bv[t] = *(const short8*)(BT + (size_t)(bn + srow[t]) * K + scol[t]);

    for (int kb = 0; kb < K; kb += GK) {
        if (kb) {
            // read-done barrier (prev iteration's ds_reads all consumed)
            asm volatile("s_waitcnt lgkmcnt(0)" ::: "memory");
            __builtin_amdgcn_sched_barrier(0);
            __builtin_amdgcn_s_barrier();
            __builtin_amdgcn_sched_barrier(0);
        }
        // ds_write current tile (compiler inserts vmcnt wait here; fp32 path
        // converts f2bf at this point -- the load itself was issued earlier)
        if (a_f32) {
#pragma unroll
            for (int t = 0; t < 4; t++) {
                short8 r;
                r[0] = (short)f2bf(fa0[t][0]); r[1] = (short)f2bf(fa0[t][1]);
                r[2] = (short)f2bf(fa0[t][2]); r[3] = (short)f2bf(fa0[t][3]);
                r[4] = (short)f2bf(fa1[t][0]); r[5] = (short)f2bf(fa1[t][1]);
                r[6] = (short)f2bf(fa1[t][2]); r[7] = (short)f2bf(fa1[t][3]);
                *(short8*)&As[srow[t] * LDK2 + scol[t]] = r;
            }
        } else {
#pragma unroll
            for (int t = 0; t < 4; t++)
                *(short8*)&As[srow[t] * LDK2 + scol[t]] = av[t];
        }
#pragma unroll
        for (int t = 0; t < 4; t++)
            *(short8*)&Bs[srow[t] * LDK2 + scol[t]] = bv[t];
        // my writes complete -> barrier -> visible to all
        asm volatile("s_waitcnt lgkmcnt(0)" ::: "memory");
        __builtin_amdgcn_sched_barrier(0);
        __builtin_amdgcn_s_barrier();
        __builtin_amdgcn_sched_barrier(0);

        // issue next-tile loads NOW; they fly during the MFMA phase
        if (kb + GK < K) {
            if (a_f32) {
#pragma unroll
                for (int t = 0; t < 4; t++) {
                    const float* pa = Af + (size_t)(bm + srow[t]) * lda + abase + kb + GK + scol[t];
                    fa0[t] = *(const floatx4*)pa;
                    fa1[t] = *(const floatx4*)(pa + 4);
                }
            } else {
#pragma unroll
                for (int t = 0; t < 4; t++)
                    av[t] = *(const short8*)(Ab + (size_t)(bm + srow[t]) * lda + abase + kb + GK + scol[t]);
            }
#pragma unroll
            for (int t = 0; t < 4; t++)
                bv[t] = *(const short8*)(BT + (size_t)(bn + srow[t]) * K + kb + GK + scol[t]);
            __builtin_amdgcn_sched_barrier(0);
        }

        // compute on LDS
#pragma unroll
        for (int kk = 0; kk < GK; kk += 32) {
            short8 af[4], bf[4];
#pragma unroll
            for (int mi = 0; mi < 4; mi++)
                af[mi] = *(const short8*)&As[(wm + mi * 16 + l16) * LDK2 + kk + quad * 8];
#pragma unroll
            for (int ni = 0; ni < 4; ni++)
                bf[ni] = *(const short8*)&Bs[(wn + ni * 16 + l16) * LDK2 + kk + quad * 8];
#pragma unroll
            for (int mi = 0; mi < 4; mi++)
#pragma unroll
                for (int ni = 0; ni < 4; ni++)
                    acc[mi][ni] = __builtin_amdgcn_mfma_f32_16x16x32_bf16(
                        af[mi], bf[ni], acc[mi][ni], 0, 0, 0);
        }
    }

    // store C (and write transformed values back into acc for the epilogue)
#pragma unroll
    for (int mi = 0; mi < 4; mi++) {
        int row = bm + wm + mi * 16 + quad * 4;
#pragma unroll
        for (int ni = 0; ni < 4; ni++) {
            int col = bn + wn + ni * 16 + l16;
            float bv2 = bias ? bias[col] : 0.f;
#pragma unroll
            for (int i = 0; i < 4; i++) {
                float v = acc[mi][ni][i] + bv2;
                if (relu) v = fmaxf(v, 0.f);
                acc[mi][ni][i] = v;
                if (Cf) Cf[(size_t)(row + i) * Nc + col] = v;
                else    C[(size_t)(row + i) * Nc + col] = f2bf(v);
            }
        }
    }

    // fused attention logits: als[row,h] += sum_col acc[row,col] * v[h][col]
    if (als) {
        if (heads == 2) {
            float s0[4], s1[4], d0[4], d1[4];
#pragma unroll
            for (int ni = 0; ni < 4; ni++) {
                int col = bn + wn + ni * 16 + l16;   // Nc == 256 here
                s0[ni] = vs[col];  s1[ni] = vs[256 + col];
                d0[ni] = vd[col];  d1[ni] = vd[256 + col];
            }
#pragma unroll
            for (int mi = 0; mi < 4; mi++) {
#pragma unroll
                for (int i = 0; i < 4; i++) {
                    float aS0 = 0.f, aS1 = 0.f, aD0 = 0.f, aD1 = 0.f;
#pragma unroll
                    for (int ni = 0; ni < 4; ni++) {
                        float vv = acc[mi][ni][i];
                        aS0 += vv * s0[ni]; aS1 += vv * s1[ni];
                        aD0 += vv * d0[ni]; aD1 += vv * d1[ni];
                    }
#pragma unroll
                    for (int msk = 1; msk < 16; msk <<= 1) {
                        aS0 += __shfl_xor(aS0, msk, 64);
                        aS1 += __shfl_xor(aS1, msk, 64);
                        aD0 += __shfl_xor(aD0, msk, 64);
                        aD1 += __shfl_xor(aD1, msk, 64);
                    }
                    if (l16 == 0) {
                        int row = bm + wm + mi * 16 + quad * 4 + i;
                        atomicAdd(&als[row * 2],     aS0);
                        atomicAdd(&als[row * 2 + 1], aS1);
                        atomicAdd(&ald[row * 2],     aD0);
                        atomicAdd(&ald[row * 2 + 1], aD1);
                    }
                }
            }
        } else {
            float aS[4], aD[4];
#pragma unroll
            for (int ni = 0; ni < 4; ni++) {
                int col = bn + wn + ni * 16 + l16;
                aS[ni] = vs[col];
                aD[ni] = vd[col];
            }
#pragma unroll
            for (int mi = 0; mi < 4; mi++) {
#pragma unroll
                for (int i = 0; i < 4; i++) {
                    float dS = 0.f, dD = 0.f;
#pragma unroll
                    for (int ni = 0; ni < 4; ni++) {
                        dS += acc[mi][ni][i] * aS[ni];
                        dD += acc[mi][ni][i] * aD[ni];
                    }
#pragma unroll
                    for (int msk = 1; msk < 16; msk <<= 1) {
                        dS += __shfl_xor(dS, msk, 64);
                        dD += __shfl_xor(dD, msk, 64);
                    }
                    if (l16 == 0) {
                        int row = bm + wm + mi * 16 + quad * 4 + i;
                        atomicAdd(&als[row], dS);
                        atomicAdd(&ald[row], dD);
                    }
                }
            }
        }
    }
}

// ---------------------------------------------------------------------------
// SINGLE-PASS segment softmax + aggregation, one wave per node (R18-proven,
// FROZEN), fixed-slot CSR: base = n*64, deg = counts[n].
// Logits are O(+-5), so exp() is safe WITHOUT max-subtraction:
// out = (sum_e w_e * h[src_e]) / sum_e w_e, w_e = exp(leaky(als[s]+ald[n])).
// heads==2: gathers 256-ch h0 rows (512 B/edge) -> per-head aggregates
//   concatenated [N,512]. heads==1: 512-ch rows (1 KB/edge) -> [N,512].
// Output bf16, NO bias/relu (applied by the following GEMM's epilogue).
// ---------------------------------------------------------------------------
__global__ __launch_bounds__(256) void k_agg(const ushort* __restrict__ h,
                                             const float* __restrict__ als,
                                             const float* __restrict__ ald,
                                             const int* __restrict__ counts,
                                             const int* __restrict__ esrc,
                                             ushort* __restrict__ outb,
                                             int heads) {
    int wave = threadIdx.x >> 6, lane = threadIdx.x & 63;
    int n = blockIdx.x * 4 + wave;
    int base = n << 6;
    int deg  = counts[n];

    int myhead = (heads == 2) ? (lane >> 5) : 0;
    int cs = (heads == 2) ? ((lane & 31) * 8) : (lane * 8);
    int stride = (heads == 2) ? 256 : 512;

    float aldh0 = ald[n * heads];
    float aldh1 = (heads == 2) ? ald[n * heads + 1] : 0.f;
    const ushort* hc = h + cs;

    float acc[8];
#pragma unroll
    for (int q = 0; q < 8; q++) acc[q] = 0.f;
    float ws0 = 0.f, ws1 = 0.f;

    for (int cb = 0; cb < deg; cb += 64) {
        int i = cb + lane;
        int sv = 0;
        float w0 = 0.f, w1 = 0.f;
        if (i < deg) {
            sv = esrc[base + i];
            w0 = __expf(leaky(als[sv * heads] + aldh0));
            if (heads == 2) w1 = __expf(leaky(als[sv * 2 + 1] + aldh1));
            ws0 += w0; ws1 += w1;
        }
        int cnt = min(64, deg - cb);
        int j = 0;
        for (; j + 4 <= cnt; j += 4) {
            int sj0 = __shfl(sv, j, 64);
            int sj1 = __shfl(sv, j + 1, 64);
            int sj2 = __shfl(sv, j + 2, 64);
            int sj3 = __shfl(sv, j + 3, 64);
            float a00 = __shfl(w0, j, 64),     a01 = __shfl(w1, j, 64);
            float a10 = __shfl(w0, j + 1, 64), a11 = __shfl(w1, j + 1, 64);
            float a20 = __shfl(w0, j + 2, 64), a21 = __shfl(w1, j + 2, 64);
            float a30 = __shfl(w0, j + 3, 64), a31 = __shfl(w1, j + 3, 64);
            float al0 = myhead ? a01 : a00;
            float al1 = myhead ? a11 : a10;
            float al2 = myhead ? a21 : a20;
            float al3 = myhead ? a31 : a30;
            short8 h0v = *(const short8*)(hc + (size_t)sj0 * stride);
            short8 h1v = *(const short8*)(hc + (size_t)sj1 * stride);
            short8 h2v = *(const short8*)(hc + (size_t)sj2 * stride);
            short8 h3v = *(const short8*)(hc + (size_t)sj3 * stride);
#pragma unroll
            for (int q = 0; q < 8; q++) {
                acc[q] += al0 * bf2f((ushort)h0v[q]);
                acc[q] += al1 * bf2f((ushort)h1v[q]);
                acc[q] += al2 * bf2f((ushort)h2v[q]);
                acc[q] += al3 * bf2f((ushort)h3v[q]);
            }
        }
        for (; j < cnt; j++) {
            int s = __shfl(sv, j, 64);
            float a0 = __shfl(w0, j, 64), a1 = __shfl(w1, j, 64);
            float al = myhead ? a1 : a0;
            short8 hv = *(const short8*)(hc + (size_t)s * stride);
#pragma unroll
            for (int q = 0; q < 8; q++) acc[q] += al * bf2f((ushort)hv[q]);
        }
    }

#pragma unroll
    for (int msk = 1; msk < 64; msk <<= 1) {
        ws0 += __shfl_xor(ws0, msk, 64);
        ws1 += __shfl_xor(ws1, msk, 64);
    }
    float inv = 1.f / ((myhead ? ws1 : ws0) + 1e-16f);

    short8 r;
#pragma unroll
    for (int q = 0; q < 8; q++) r[q] = (short)f2bf(acc[q] * inv);
    *(short8*)(outb + (size_t)n * 512 + lane * 8) = r;
}

// ---------------------------------------------------------------------------
// R23: R18 structure (best measured: 220.9 us, 7 dispatches) with the x-cast
// phase deleted -- gemm1 reads x fp32 directly (convert at ds_write site;
// loads still pipelined). Mega-kernel/cooperative path abandoned (R21/R22:
// grid.sync + threadfence cost ~7x on this 8-XCD part).
//   gat1: als1 = relu(h0).v1 (fused in fc GEMM epilogue); aggregate h0
//         per head -> aggcat [N,512]; grouped GEMM aggcat@W1 (+b1, relu)
//         -> g1, with als2 = g1.v2 fused.
//   gat2: aggregate g1 -> agg2; GEMM agg2@W2 (+b2, relu) -> out fp32.
// ---------------------------------------------------------------------------
extern "C" void kernel_launch(void* const* d_in, const int* in_sizes, int n_in,
                              void* d_out, int out_size, void* d_ws, size_t ws_size,
                              hipStream_t stream) {
    const float* x   = (const float*)d_in[0];
    const int*   adj = (const int*)d_in[1];
    const float* Wfc = (const float*)d_in[2];
    const float* bfc = (const float*)d_in[3];
    const float* W1  = (const float*)d_in[4];
    const float* a1s = (const float*)d_in[5];
    const float* a1d = (const float*)d_in[6];
    const float* b1  = (const float*)d_in[7];
    const float* W2  = (const float*)d_in[8];
    const float* a2s = (const float*)d_in[9];
    const float* a2d = (const float*)d_in[10];
    const float* b2  = (const float*)d_in[11];
    float* out = (float*)d_out;

    char* ws = (char*)d_ws;
    size_t off = 0;
    auto alloc = [&](size_t bytes) -> void* {
        void* p = ws + off;
        off += (bytes + 255) & ~(size_t)255;
        return p;
    };
    ushort* h0b  = (ushort*)alloc((size_t)N_NODES * 256 * 2);
    ushort* hub  = (ushort*)alloc((size_t)N_NODES * 512 * 2);  // aggcat, then agg2
    ushort* g1b  = (ushort*)alloc((size_t)N_NODES * 512 * 2);
    int* counts  = (int*)alloc(N_NODES * 4);
    int* esrc    = (int*)alloc((size_t)N_NODES * SLOTS * 4);   // fixed-slot CSR
    ushort* WfcT = (ushort*)alloc(256 * 256 * 2);
    ushort* W1T  = (ushort*)alloc(512 * 256 * 2);
    ushort* W2T  = (ushort*)alloc(512 * 512 * 2);
    // als/ald block: contiguous (sizes are 256B multiples -> no alloc gaps),
    // zeroed as one segment in k_prep (98304 floats total).
    float* als1  = (float*)alloc(N_NODES * 2 * 4);   // 32768 f
    float* ald1  = (float*)alloc(N_NODES * 2 * 4);   // 32768 f
    float* als2  = (float*)alloc(N_NODES * 4);       // 16384 f
    float* ald2  = (float*)alloc(N_NODES * 4);       // 16384 f
    float* v1s   = (float*)alloc(512 * 4);
    float* v1d   = (float*)alloc(512 * 4);
    float* v2s   = (float*)alloc(512 * 4);
    float* v2d   = (float*)alloc(512 * 4);

    // fused prep: transpose weights, zero counts + als/ald, v-dots
    k_prep<<<PREP_TOT / 256, 256, 0, stream>>>(Wfc, WfcT, W1, W1T, W2, W2T,
                                               counts, (int*)als1,
                                               a1s, a1d, a2s, a2d,
                                               v1s, v1d, v2s, v2d);

    // fixed-slot CSR build (one dispatch)
    k_scatter<<<(E_TOT + 255) / 256, 256, 0, stream>>>(adj, counts, esrc);

    // h0 = relu(x @ Wfc + bfc)            [N,256] bf16  + fused gat1 logits
    //      (A = x fp32, converted in staging)
    gemm128<<<dim3(N_NODES / GM, 256 / GN), 256, 0, stream>>>(
        x, 1, 256, 0, WfcT, bfc, h0b, nullptr, 256, 256, 1,
        v1s, v1d, als1, ald1, 2);
    // gat1 aggregation of h0 (per-head) -> aggcat [N,512] bf16
    k_agg<<<N_NODES / 4, 256, 0, stream>>>(h0b, als1, ald1, counts, esrc, hub, 2);

    // g1 = relu(grouped aggcat @ W1 + b1) [N,512] bf16  + fused gat2 logits
    gemm128<<<dim3(N_NODES / GM, 512 / GN), 256, 0, stream>>>(
        hub, 0, 512, 256, W1T, b1, g1b, nullptr, 512, 256, 1,
        v2s, v2d, als2, ald2, 1);
    // gat2 aggregation of g1 -> agg2 [N,512] bf16
    k_agg<<<N_NODES / 4, 256, 0, stream>>>(g1b, als2, ald2, counts, esrc, hub, 1);

    // out = relu(agg2 @ W2 + b2)          [N,512] fp32 (final output)
    gemm128<<<dim3(N_NODES / GM, 512 / GN), 256, 0, stream>>>(
        hub, 0, 512, 0, W2T, b2, nullptr, out, 512, 512, 1,
        nullptr, nullptr, nullptr, nullptr, 0);
}